// Round 6
// baseline (433.536 us; speedup 1.0000x reference)
//
#include <hip/hip_runtime.h>

typedef __bf16 bf16x8 __attribute__((ext_vector_type(8)));
typedef float  f32x4  __attribute__((ext_vector_type(4)));

__device__ __forceinline__ float lrelu(float x, float s){ return x > 0.f ? x : s*x; }
__device__ __forceinline__ float u2f_lo(unsigned u){ union{unsigned u; float f;} c; c.u = u << 16; return c.f; }
__device__ __forceinline__ float u2f_hi(unsigned u){ union{unsigned u; float f;} c; c.u = u & 0xffff0000u; return c.f; }

// ---------------- prep: W -> W^T bf16, S -> bf16 (S is already [n][k]), int64 detect ----------------
__global__ void prep_k(const float* __restrict__ W1, const float* __restrict__ W2,
                       const float* __restrict__ W3, const float* __restrict__ S,
                       __bf16* __restrict__ WT1, __bf16* __restrict__ WT2,
                       __bf16* __restrict__ WT3, __bf16* __restrict__ Sb,
                       const int* __restrict__ ei, int* __restrict__ flag){
  int t = blockIdx.x*256 + threadIdx.x;
  if (t < 16384){ int n = t>>7, k = t&127; WT1[t] = (__bf16)W1[k*128+n]; }
  else if (t < 32768){ int i = t-16384; int n = i>>7, k = i&127; WT2[i] = (__bf16)W2[k*128+n]; }
  else if (t < 40960){ int i = t-32768; int n = i>>7, k = i&127; WT3[i] = (__bf16)W3[k*64+n]; }
  else if (t < 73728){ int i = t-40960; Sb[i] = (__bf16)S[i]; }
  if (t == 0){
    int is64 = 1;
    for (int k=1; k<64; k+=2) if (ei[k] != 0){ is64 = 0; break; }
    *flag = is64;
  }
}

// ---------------- CSR build ----------------
__global__ void hist_k(const int* __restrict__ ei, const int* __restrict__ flag,
                       int E, int* __restrict__ cnt){
  int t = blockIdx.x*256 + threadIdx.x;
  if (t >= E) return;
  int f = *flag;
  long di = f ? 2L*((long)E + t) : (long)(E + t);
  atomicAdd(&cnt[ei[di]], 1);
}

__global__ void scan1_k(const int* __restrict__ cnt, int* __restrict__ off,
                        int* __restrict__ bsum, int n){
  __shared__ int sc[1024];
  int t = threadIdx.x;
  int i = blockIdx.x*1024 + t;
  int v = (i < n) ? cnt[i] : 0;
  sc[t] = v; __syncthreads();
  for (int d=1; d<1024; d<<=1){
    int x = (t >= d) ? sc[t-d] : 0;
    __syncthreads();
    sc[t] += x;
    __syncthreads();
  }
  if (i < n) off[i] = sc[t] - v;
  if (t == 1023) bsum[blockIdx.x] = sc[1023];
}

__global__ void scan3_k(int* __restrict__ off, const int* __restrict__ bsum,
                        int* __restrict__ cursor, int n, int E){
  __shared__ int base_s;
  if (threadIdx.x == 0){
    int run = 0;
    for (int b=0; b<(int)blockIdx.x; b++) run += bsum[b];
    base_s = run;
  }
  __syncthreads();
  int i = blockIdx.x*1024 + threadIdx.x;
  if (i < n){
    int v = off[i] + base_s;
    off[i] = v;
    cursor[i] = v;
  }
  if (i == 0) off[n] = E;
}

__global__ void scatter_k(const int* __restrict__ ei, const int* __restrict__ flag,
                          int E, int* __restrict__ cursor, int* __restrict__ csr){
  int t = blockIdx.x*256 + threadIdx.x;
  if (t >= E) return;
  int f = *flag;
  int s = ei[f ? 2L*(long)t         : (long)t];
  int d = ei[f ? 2L*((long)E + t)   : (long)(E + t)];
  int pos = atomicAdd(&cursor[d], 1);
  csr[pos] = s;
}

// ---------------- GEMM v2 (no LDS): C[M,Ntot] = A[M,K] @ Bt^T, Bt is [Ntot][K] bf16 ----------------
// MFMA 16x16x32 bf16. A frag: A[m=lane&15][k=kq*8+j]; B frag: Bt[n=lane&15][k=kq*8+j];
// C/D: col=lane&15, row=kq*4+reg.  (kq = lane>>4)
template<int K, bool AF32, bool ALPH, bool OUTBF>
__global__ __launch_bounds__(256) void gemm_k(const __bf16* __restrict__ A,
        const float* __restrict__ Af, const __bf16* __restrict__ Bt,
        float* __restrict__ Cf, __bf16* __restrict__ Cb,
        const float* __restrict__ avs, const float* __restrict__ avd,
        float* __restrict__ as_, float* __restrict__ ad_,
        int M, int Ntot){
  const int lane = threadIdx.x & 63, wave = threadIdx.x >> 6;
  const int row0 = (blockIdx.x*4 + wave) * 16;
  if (row0 >= M) return;
  const int n0 = blockIdx.y * 128;
  const int BN = min(128, Ntot - n0);
  const int m = lane & 15, kq = lane >> 4;
  bf16x8 af[K/32];
  if (AF32){
    const float* Ap = Af + (size_t)(row0 + m)*K + kq*8;
    #pragma unroll
    for (int ks=0; ks<K/32; ks++){
      f32x4 lo = *(const f32x4*)(Ap + ks*32);
      f32x4 hi = *(const f32x4*)(Ap + ks*32 + 4);
      bf16x8 v;
      #pragma unroll
      for (int j=0; j<4; j++){ v[j] = (__bf16)lo[j]; v[4+j] = (__bf16)hi[j]; }
      af[ks] = v;
    }
  } else {
    const __bf16* Ap = A + (size_t)(row0 + m)*K + kq*8;
    #pragma unroll
    for (int ks=0; ks<K/32; ks++) af[ks] = *(const bf16x8*)(Ap + ks*32);
  }
  float ps[4] = {0,0,0,0}, pd[4] = {0,0,0,0};
  const int ntc = BN >> 4;
  for (int nt=0; nt<ntc; nt++){
    f32x4 acc = {0.f, 0.f, 0.f, 0.f};
    const __bf16* Bp = Bt + (size_t)(n0 + nt*16 + m)*K + kq*8;
    #pragma unroll
    for (int ks=0; ks<K/32; ks++){
      bf16x8 bf = *(const bf16x8*)(Bp + ks*32);
      acc = __builtin_amdgcn_mfma_f32_16x16x32_bf16(af[ks], bf, acc, 0, 0, 0);
    }
    if (ALPH){
      float vs = avs[n0 + nt*16 + m], vd = avd[n0 + nt*16 + m];
      #pragma unroll
      for (int r=0; r<4; r++){ ps[r] += acc[r]*vs; pd[r] += acc[r]*vd; }
    }
    size_t cb = (size_t)(row0 + kq*4)*Ntot + (n0 + nt*16 + m);
    #pragma unroll
    for (int r=0; r<4; r++){
      if (OUTBF) Cb[cb + (size_t)r*Ntot] = (__bf16)acc[r];
      else       Cf[cb + (size_t)r*Ntot] = acc[r];
    }
  }
  if (ALPH){
    #pragma unroll
    for (int o=1; o<16; o<<=1){
      #pragma unroll
      for (int r=0; r<4; r++){ ps[r] += __shfl_xor(ps[r], o); pd[r] += __shfl_xor(pd[r], o); }
    }
    if (m == 0){
      #pragma unroll
      for (int r=0; r<4; r++){
        as_[row0 + kq*4 + r] = ps[r];
        ad_[row0 + kq*4 + r] = pd[r];
      }
    }
  }
}

// ---------------- aggregation v3: 16B/lane batched gather ----------------
// F=128: G=4 edges per load-instruction (16 lanes/row); F=64: G=8 (8 lanes/row).
// One wave per node, 4 nodes/block, no block barriers. Self-loop appended to edge list.
template<int F, int ACT>
__global__ __launch_bounds__(256) void aggregate_k(const __bf16* __restrict__ h,
        const float* __restrict__ as, const float* __restrict__ ad,
        const int* __restrict__ off, const int* __restrict__ csr,
        const float* __restrict__ bias, __bf16* __restrict__ y, int N){
  constexpr int G = (F == 128) ? 4 : 8;     // edges per batch
  constexpr int P = 64 / G;                 // lanes per row (P*16B = row bytes)
  __shared__ uint2 es[4][72];               // (w bits, src) per wave
  const int wave = threadIdx.x >> 6, lane = threadIdx.x & 63;
  const int i = blockIdx.x*4 + wave;
  if (i >= N) return;
  const int beg = off[i], end = off[i+1];
  const int deg = end - beg;
  const float adi = ad[i];
  const float e_self = lrelu(as[i] + adi, 0.2f);
  uint2* e = es[wave];

  float acc[8] = {0,0,0,0,0,0,0,0};
  float dsum, mx;
  int degx;

  if (deg <= 64){
    // gather edge + weight in one pass
    int p = beg + lane;
    bool v = p < end;
    int s = v ? csr[p] : 0;
    float ee = v ? lrelu(as[s] + adi, 0.2f) : -1e30f;
    mx = fmaxf(ee, e_self);
    #pragma unroll
    for (int o=32; o>0; o>>=1) mx = fmaxf(mx, __shfl_xor(mx, o));
    float wgt = v ? __expf(ee - mx) : 0.f;
    dsum = wgt;
    #pragma unroll
    for (int o=32; o>0; o>>=1) dsum += __shfl_xor(dsum, o);
    float wself = __expf(e_self - mx);
    dsum += wself;
    e[lane] = make_uint2(__float_as_uint(wgt), (unsigned)s);
    if (lane == 0) e[deg] = make_uint2(__float_as_uint(wself), (unsigned)i);
    degx = deg + 1;
    asm volatile("s_waitcnt lgkmcnt(0)" ::: "memory");

    const int g = lane / P, p16 = lane % P;
    const int T = (degx + G - 1) / G;
    int s0 = (int)e[0].y;
    for (int t=0; t<T; t++){
      int idx = t*G + g;
      bool ok = idx < degx;
      uint2 ev = e[ok ? idx : 0];
      float wk = ok ? __uint_as_float(ev.x) : 0.f;
      int   sk = ok ? (int)ev.y : s0;
      const uint4* hp = (const uint4*)(h + (size_t)sk*F);
      uint4 rv = hp[p16];
      acc[0] += wk*u2f_lo(rv.x); acc[1] += wk*u2f_hi(rv.x);
      acc[2] += wk*u2f_lo(rv.y); acc[3] += wk*u2f_hi(rv.y);
      acc[4] += wk*u2f_lo(rv.z); acc[5] += wk*u2f_hi(rv.z);
      acc[6] += wk*u2f_lo(rv.w); acc[7] += wk*u2f_hi(rv.w);
    }
  } else {
    // general path: chunked; self handled as an extra virtual chunk entry
    mx = e_self;
    for (int p = beg + lane; p < end; p += 64)
      mx = fmaxf(mx, lrelu(as[csr[p]] + adi, 0.2f));
    #pragma unroll
    for (int o=32; o>0; o>>=1) mx = fmaxf(mx, __shfl_xor(mx, o));
    float dpart = 0.f;
    const int g = lane / P, p16 = lane % P;
    for (int base = beg; base < end; base += 64){
      int p = base + lane;
      bool v = p < end;
      int s = v ? csr[p] : 0;
      float wgt = v ? __expf(lrelu(as[s] + adi, 0.2f) - mx) : 0.f;
      dpart += wgt;
      asm volatile("s_waitcnt lgkmcnt(0)" ::: "memory");  // drain prior batch reads
      e[lane] = make_uint2(__float_as_uint(wgt), (unsigned)s);
      asm volatile("s_waitcnt lgkmcnt(0)" ::: "memory");
      int cnt = min(64, end - base);
      int T = (cnt + G - 1) / G;
      int s0 = (int)e[0].y;
      for (int t=0; t<T; t++){
        int idx = t*G + g;
        bool ok = idx < cnt;
        uint2 ev = e[ok ? idx : 0];
        float wk = ok ? __uint_as_float(ev.x) : 0.f;
        int   sk = ok ? (int)ev.y : s0;
        const uint4* hp = (const uint4*)(h + (size_t)sk*F);
        uint4 rv = hp[p16];
        acc[0] += wk*u2f_lo(rv.x); acc[1] += wk*u2f_hi(rv.x);
        acc[2] += wk*u2f_lo(rv.y); acc[3] += wk*u2f_hi(rv.y);
        acc[4] += wk*u2f_lo(rv.z); acc[5] += wk*u2f_hi(rv.z);
        acc[6] += wk*u2f_lo(rv.w); acc[7] += wk*u2f_hi(rv.w);
      }
    }
    dsum = dpart;
    #pragma unroll
    for (int o=32; o>0; o>>=1) dsum += __shfl_xor(dsum, o);
    float wself = __expf(e_self - mx);
    dsum += wself;
    // self row (group 0 only)
    if (g == 0){
      const uint4* hp = (const uint4*)(h + (size_t)i*F);
      uint4 rv = hp[p16];
      acc[0] += wself*u2f_lo(rv.x); acc[1] += wself*u2f_hi(rv.x);
      acc[2] += wself*u2f_lo(rv.y); acc[3] += wself*u2f_hi(rv.y);
      acc[4] += wself*u2f_lo(rv.z); acc[5] += wself*u2f_hi(rv.z);
      acc[6] += wself*u2f_lo(rv.w); acc[7] += wself*u2f_hi(rv.w);
    }
  }

  // cross-group reduce: sum over g (same p16)
  #pragma unroll
  for (int o = P; o < 64; o <<= 1){
    #pragma unroll
    for (int j=0; j<8; j++) acc[j] += __shfl_xor(acc[j], o);
  }
  const int g = lane / P, p16 = lane % P;
  if (g == 0){
    float inv = 1.f / dsum;
    f32x4 b0 = *(const f32x4*)(bias + p16*8);
    f32x4 b1 = *(const f32x4*)(bias + p16*8 + 4);
    bf16x8 ov;
    #pragma unroll
    for (int j=0; j<8; j++){
      float o0 = acc[j]*inv + (j<4 ? b0[j] : b1[j-4]);
      if (ACT) o0 = lrelu(o0, 0.1f);
      ov[j] = (__bf16)o0;
    }
    *(uint4*)(y + (size_t)i*F + p16*8) = *(uint4*)&ov;
  }
}

extern "C" void kernel_launch(void* const* d_in, const int* in_sizes, int n_in,
                              void* d_out, int out_size, void* d_ws, size_t ws_size,
                              hipStream_t stream){
  const float* x   = (const float*)d_in[0];
  const int*   ei  = (const int*)d_in[1];
  const float* W1  = (const float*)d_in[2];
  const float* a1s = (const float*)d_in[3];
  const float* a1d = (const float*)d_in[4];
  const float* b1  = (const float*)d_in[5];
  const float* W2  = (const float*)d_in[6];
  const float* a2s = (const float*)d_in[7];
  const float* a2d = (const float*)d_in[8];
  const float* b2  = (const float*)d_in[9];
  const float* W3  = (const float*)d_in[10];
  const float* a3s = (const float*)d_in[11];
  const float* a3d = (const float*)d_in[12];
  const float* b3  = (const float*)d_in[13];
  const float* S   = (const float*)d_in[14];
  float* out = (float*)d_out;

  const int N = in_sizes[0] / 128;   // 50000
  const int E = in_sizes[1] / 2;     // 800000

  char* w = (char*)d_ws;
  size_t o = 0;
  auto alloc = [&](size_t bytes)->void*{
    void* p = w + o; o += bytes; o = (o + 255) & ~(size_t)255; return p;
  };
  int*    off    = (int*)   alloc((size_t)(N+1)*4);
  int*    cursor = (int*)   alloc((size_t)N*4);
  int*    bsum   = (int*)   alloc(64*4);
  int*    flag   = (int*)   alloc(4);
  int*    csr    = (int*)   alloc((size_t)E*4);
  float*  as_    = (float*) alloc((size_t)N*4);
  float*  ad_    = (float*) alloc((size_t)N*4);
  __bf16* hb     = (__bf16*)alloc((size_t)N*128*2);
  __bf16* yb     = (__bf16*)alloc((size_t)N*128*2);
  __bf16* WT1    = (__bf16*)alloc(128*128*2);
  __bf16* WT2    = (__bf16*)alloc(128*128*2);
  __bf16* WT3    = (__bf16*)alloc(64*128*2);
  __bf16* Sb     = (__bf16*)alloc(512*64*2);
  (void)ws_size; (void)n_in; (void)out_size;

  prep_k<<<288, 256, 0, stream>>>(W1, W2, W3, S, WT1, WT2, WT3, Sb, ei, flag);
  hipMemsetAsync(cursor, 0, (size_t)N*4, stream);
  hist_k<<<(E+255)/256, 256, 0, stream>>>(ei, flag, E, cursor);
  int nb = (N + 1023) / 1024;
  scan1_k<<<nb, 1024, 0, stream>>>(cursor, off, bsum, N);
  scan3_k<<<nb, 1024, 0, stream>>>(off, bsum, cursor, N, E);
  scatter_k<<<(E+255)/256, 256, 0, stream>>>(ei, flag, E, cursor, csr);

  const int gx = (N + 63) / 64;
  const int ga = (N + 3) / 4;
  // Layer 1 (A = fp32 x)
  gemm_k<128,true,true,true><<<dim3(gx,1), 256, 0, stream>>>(
      nullptr, x, WT1, nullptr, hb, a1s, a1d, as_, ad_, N, 128);
  aggregate_k<128,1><<<ga, 256, 0, stream>>>(hb, as_, ad_, off, csr, b1, yb, N);
  // Layer 2
  gemm_k<128,false,true,true><<<dim3(gx,1), 256, 0, stream>>>(
      yb, nullptr, WT2, nullptr, hb, a2s, a2d, as_, ad_, N, 128);
  aggregate_k<128,1><<<ga, 256, 0, stream>>>(hb, as_, ad_, off, csr, b2, yb, N);
  // Layer 3 (Ntot = 64)
  gemm_k<128,false,true,true><<<dim3(gx,1), 256, 0, stream>>>(
      yb, nullptr, WT3, nullptr, hb, a3s, a3d, as_, ad_, N, 64);
  aggregate_k<64,0><<<ga, 256, 0, stream>>>(hb, as_, ad_, off, csr, b3, yb, N);
  // Final projection: out[N,512] = y[N,64] @ S^T (Sb is [512][64] = Bt)
  gemm_k<64,false,false,false><<<dim3(gx,4), 256, 0, stream>>>(
      yb, nullptr, Sb, out, nullptr, nullptr, nullptr, nullptr, nullptr, N, 512);
}